// Round 10
// baseline (1010.713 us; speedup 1.0000x reference)
//
#include <hip/hip_runtime.h>
#include <hip/hip_fp16.h>
#include <math.h>

typedef _Float16 half_t;
typedef half_t half2_t __attribute__((ext_vector_type(2)));
typedef half_t half4_t __attribute__((ext_vector_type(4)));
typedef half_t half8_t __attribute__((ext_vector_type(8)));
typedef float f32x4 __attribute__((ext_vector_type(4)));

#define LN_EPS 1e-5f
#define FDOT2(a, b, c) __builtin_amdgcn_fdot2((a), (b), (c), false)

// ---------------------------------------------------------------------------
// Pack W*g (LN gain folded) into f16 MFMA B-fragment order:
//   packed[((cbg*T + t)*64 + l)*8 + j] = (f16)(W[16*cbg+(l&15)][32t+8*(l>>4)+j] * g[k])
// ---------------------------------------------------------------------------
__global__ void pack_weights(const float* __restrict__ W0, const float* __restrict__ g0,
                             const float* __restrict__ W1, const float* __restrict__ g1,
                             const float* __restrict__ W2, const float* __restrict__ g2,
                             half_t* __restrict__ ws) {
    int sid = blockIdx.x * 256 + threadIdx.x;
    const float* W; const float* g; int K, T, off;
    if (sid < 49152)      { W = W0; g = g0; K = 768; T = 24; off = 0; }
    else if (sid < 65536) { W = W1; g = g1; K = 512; T = 16; off = 49152; sid -= 49152; }
    else if (sid < 69632) { W = W2; g = g2; K = 256; T = 8;  off = 65536; sid -= 65536; }
    else return;
    const int l   = sid & 63;
    const int t   = (sid >> 6) % T;
    const int cbg = (sid >> 6) / T;
    const int n   = (l & 15) + 16 * cbg;
    const int k0  = 32 * t + 8 * (l >> 4);
    const float* src = W + (size_t)n * K + k0;
    const float* gs  = g + k0;
    half8_t v;
    #pragma unroll
    for (int jq = 0; jq < 8; jq++) v[jq] = (half_t)(src[jq] * gs[jq]);
    *(half8_t*)(ws + (size_t)(off + sid) * 8) = v;
}

// ---------------------------------------------------------------------------
// Fold LN bias into per-output scalars: s[n]=sum_k W[n,k]*g[k],
// c'[n]=sum_k W[n,k]*b[k]+c[n]. f layout:
// s0[512] c0[512] s1[256] c1[256] s2[128] c2[128] w3g[128] s3 c3'
// ---------------------------------------------------------------------------
__global__ void fold_bias(const float* __restrict__ W0, const float* __restrict__ g0,
                          const float* __restrict__ b0, const float* __restrict__ c0,
                          const float* __restrict__ W1, const float* __restrict__ g1,
                          const float* __restrict__ b1, const float* __restrict__ c1,
                          const float* __restrict__ W2, const float* __restrict__ g2,
                          const float* __restrict__ b2, const float* __restrict__ c2,
                          const float* __restrict__ W3, const float* __restrict__ g3,
                          const float* __restrict__ b3, const float* __restrict__ c3,
                          float* __restrict__ f) {
    const int gw   = (blockIdx.x * 256 + threadIdx.x) >> 6;
    const int lane = threadIdx.x & 63;
    if (gw == 896) {
        float s = 0.f, cb_ = 0.f;
        for (int k = lane; k < 128; k += 64) {
            const float wg = W3[k] * g3[k];
            f[1792 + k] = wg;
            s += wg; cb_ += W3[k] * b3[k];
        }
        #pragma unroll
        for (int m = 1; m < 64; m <<= 1) { s += __shfl_xor(s, m); cb_ += __shfl_xor(cb_, m); }
        if (lane == 0) { f[1920] = s; f[1921] = cb_ + c3[0]; }
        return;
    }
    const float *W, *g, *b, *cc; int K, n; float *sf, *cf;
    if (gw < 512)      { W = W0; g = g0; b = b0; cc = c0; K = 768; n = gw;       sf = f;        cf = f + 512; }
    else if (gw < 768) { W = W1; g = g1; b = b1; cc = c1; K = 512; n = gw - 512; sf = f + 1024; cf = f + 1280; }
    else if (gw < 896) { W = W2; g = g2; b = b2; cc = c2; K = 256; n = gw - 768; sf = f + 1536; cf = f + 1664; }
    else return;
    const float* Wr = W + (size_t)n * K;
    float s = 0.f, cb_ = 0.f;
    for (int k = lane; k < K; k += 64) { const float wg = Wr[k] * g[k]; s += wg; cb_ += Wr[k] * b[k]; }
    #pragma unroll
    for (int m = 1; m < 64; m <<= 1) { s += __shfl_xor(s, m); cb_ += __shfl_xor(cb_, m); }
    if (lane == 0) { sf[n] = s; cf[n] = cb_ + cc[n]; }
}

// ---------------------------------------------------------------------------
// Fused MLP v10: PERSISTENT 1 block/CU (grid 256), 16 tiles/block, 9-slice
// software pipeline: tail(tile i-1) runs under staging+GEMM0(tile i).
// LDS: x1 double-buffer (2x64K) + staging dbuf (2x12K). acc0 carries across
// the iteration boundary in AGPRs.
// ---------------------------------------------------------------------------
__global__ __launch_bounds__(512, 2)
void fused_mlp(const float* __restrict__ x_in,
               const half_t* __restrict__ W0p, const half_t* __restrict__ W1p,
               const half_t* __restrict__ W2p, const float* __restrict__ f,
               float* __restrict__ out, int ntiles)
{
    __shared__ half_t x1buf[2][32768];     // 2 x 64 KiB x1-fragment tiles
    __shared__ half_t stg[2][6144];        // 2 x 12 KiB staging chunks (96 cols)
    __shared__ float row_m[64], row_rs[64];     // tail LN stats
    __shared__ float row_m0[64], row_rs0[64];   // LN0 stats of staged tile
    __shared__ float ps[2][64], pq[2][64];
    __shared__ half2_t w3h[64];

    const int tid  = threadIdx.x;
    const int lane = tid & 63;
    const int wv   = tid >> 6;
    const int grp  = lane >> 4;
    const int cl   = lane & 15;
    const int row  = tid >> 3;       // staging/scan row 0..63
    const int jj   = tid & 7;
    const int rbw  = row >> 4;
    const int rb_s = wv & 3;         // scan row-block
    const int th_s = wv >> 2;        // scan t-half
    const long tile0 = (long)blockIdx.x * ntiles;

    const float* s0f = f;        const float* c0f = f + 512;
    const float* s1f = f + 1024; const float* c1f = f + 1280;
    const float* s2f = f + 1536; const float* c2f = f + 1664;
    const half2_t one2 = {(half_t)1.f, (half_t)1.f};

    if (tid < 64) {
        half2_t w; w[0] = (half_t)f[1792 + 2 * tid]; w[1] = (half_t)f[1793 + 2 * tid];
        w3h[tid] = w;
    }

    float s = 0.f, ss = 0.f;             // LN0 accum for staged tile
    f32x4 vb[3];
    f32x4 acc0[4][4];                    // persists across iteration boundary
    f32x4 acc1[4][2];
    f32x4 acc2[4];
    #pragma unroll
    for (int rb = 0; rb < 4; rb++)
        #pragma unroll
        for (int cb = 0; cb < 4; cb++) acc0[rb][cb] = 0.f;

    const float* xrow_base = x_in + (size_t)row * 768;

    #pragma unroll 1
    for (int i = 0; i <= ntiles; i++) {
        const bool hasS = (i < ntiles);
        const bool hasT = (i > 0);
        const float* xrow = xrow_base + (size_t)(tile0 + i) * 49152;   // 64*768
        half_t* xT = x1buf[(i + 1) & 1];   // tail tile (i-1) buffer

        auto stage_load = [&](int c) {
            const float* xp = xrow + 96 * c + 4 * jj;
            #pragma unroll
            for (int u = 0; u < 3; u++)
                vb[u] = __builtin_nontemporal_load((const f32x4*)(xp + 32 * u));
        };
        auto stage_write = [&](int c) {
            half_t* fb = stg[c & 1];
            const int hg = jj >> 1, jo = 4 * (jj & 1);
            #pragma unroll
            for (int u = 0; u < 3; u++) {
                const f32x4 v = vb[u];
                half2_t h01; h01[0] = (half_t)v[0]; h01[1] = (half_t)v[1];
                half2_t h23; h23[0] = (half_t)v[2]; h23[1] = (half_t)v[3];
                s  = FDOT2(h01, one2, s);  s  = FDOT2(h23, one2, s);
                ss = FDOT2(h01, h01, ss);  ss = FDOT2(h23, h23, ss);
                half4_t hv; hv[0] = h01[0]; hv[1] = h01[1]; hv[2] = h23[0]; hv[3] = h23[1];
                *(half4_t*)(&fb[((u * 4 + rbw) * 64 + ((row & 15) + 16 * hg)) * 8 + jo]) = hv;
            }
        };
        auto gemm0c = [&](int c) {
            const half_t* fb = stg[c & 1];
            const half_t* wp = W0p + (size_t)(4 * wv * 24 + 3 * c) * 512 + lane * 8;
            #pragma unroll
            for (int tt = 0; tt < 3; tt++) {
                half8_t af[4];
                #pragma unroll
                for (int rb = 0; rb < 4; rb++)
                    af[rb] = *(const half8_t*)(&fb[((tt * 4 + rb) * 64 + lane) * 8]);
                #pragma unroll
                for (int cb = 0; cb < 4; cb++) {
                    const half8_t bf = *(const half8_t*)(wp + tt * 512 + (size_t)cb * 12288);
                    #pragma unroll
                    for (int rb = 0; rb < 4; rb++)
                        acc0[rb][cb] = __builtin_amdgcn_mfma_f32_16x16x32_f16(af[rb], bf, acc0[rb][cb], 0, 0, 0);
                }
            }
        };

        // ---------------- s0: ep0(t_{i-1}) ; stage chunk 0 ----------------
        if (hasS) stage_load(0);
        if (hasT) {
            #pragma unroll
            for (int cb = 0; cb < 4; cb++) {
                const int c = cl + 16 * (4 * wv + cb);
                const float sv = s0f[c], cv = c0f[c];
                const int t = c >> 5, j = c & 7, sc = 16 * ((c >> 3) & 3);
                #pragma unroll
                for (int rb = 0; rb < 4; rb++)
                    #pragma unroll
                    for (int v = 0; v < 4; v++) {
                        const int r = 16 * rb + 4 * grp + v;
                        float y = row_rs0[r] * (acc0[rb][cb][v] - row_m0[r] * sv) + cv;
                        y = y > 0.f ? y : (__expf(y) - 1.f);
                        xT[((t * 4 + rb) * 64 + (4 * grp + v + sc)) * 8 + j] = (half_t)y;
                    }
            }
        }
        #pragma unroll
        for (int rb = 0; rb < 4; rb++)
            #pragma unroll
            for (int cb = 0; cb < 4; cb++) acc0[rb][cb] = 0.f;
        if (hasS) stage_write(0);
        __syncthreads();

        // ---------------- s1: LN1 partials ; gemm0 c0 ----------------
        if (hasS) stage_load(1);
        if (hasT) {
            float s_ = 0.f, q_ = 0.f;
            #pragma unroll
            for (int u = 0; u < 8; u++) {
                const int t = 8 * th_s + u;
                const half8_t h = *(const half8_t*)(&xT[((t * 4 + rb_s) * 64 + lane) * 8]);
                half2_t p0 = {h[0], h[1]}, p1 = {h[2], h[3]}, p2 = {h[4], h[5]}, p3 = {h[6], h[7]};
                s_ = FDOT2(p0, one2, s_); s_ = FDOT2(p1, one2, s_);
                s_ = FDOT2(p2, one2, s_); s_ = FDOT2(p3, one2, s_);
                q_ = FDOT2(p0, p0, q_);   q_ = FDOT2(p1, p1, q_);
                q_ = FDOT2(p2, p2, q_);   q_ = FDOT2(p3, p3, q_);
            }
            s_ += __shfl_xor(s_, 16); s_ += __shfl_xor(s_, 32);
            q_ += __shfl_xor(q_, 16); q_ += __shfl_xor(q_, 32);
            if (lane < 16) { ps[th_s][16 * rb_s + lane] = s_; pq[th_s][16 * rb_s + lane] = q_; }
        }
        if (hasS) { gemm0c(0); stage_write(1); }
        __syncthreads();

        // ---------------- s2: LN1 combine + gemm1 t0..7 ; gemm0 c1 ----------------
        if (hasS) stage_load(2);
        if (hasT) {
            if (tid < 64) {
                const float a_ = ps[0][tid] + ps[1][tid];
                const float b_ = pq[0][tid] + pq[1][tid];
                const float mm = a_ * (1.f / 512.f);
                row_m[tid]  = mm;
                row_rs[tid] = 1.f / sqrtf(b_ * (1.f / 512.f) - mm * mm + LN_EPS);
            }
            #pragma unroll
            for (int rb = 0; rb < 4; rb++) { acc1[rb][0] = 0.f; acc1[rb][1] = 0.f; }
            const half_t* wp = W1p + (size_t)(2 * wv * 16) * 512 + lane * 8;
            #pragma unroll
            for (int t = 0; t < 8; t++) {
                half8_t af[4];
                #pragma unroll
                for (int rb = 0; rb < 4; rb++)
                    af[rb] = *(const half8_t*)(&xT[((t * 4 + rb) * 64 + lane) * 8]);
                #pragma unroll
                for (int cb = 0; cb < 2; cb++) {
                    const half8_t bf = *(const half8_t*)(wp + t * 512 + cb * 8192);
                    #pragma unroll
                    for (int rb = 0; rb < 4; rb++)
                        acc1[rb][cb] = __builtin_amdgcn_mfma_f32_16x16x32_f16(af[rb], bf, acc1[rb][cb], 0, 0, 0);
                }
            }
        }
        if (hasS) { gemm0c(1); stage_write(2); }
        __syncthreads();

        // ---------------- s3: gemm1 t8..15 ; gemm0 c2 ----------------
        if (hasS) stage_load(3);
        if (hasT) {
            const half_t* wp = W1p + (size_t)(2 * wv * 16) * 512 + lane * 8;
            #pragma unroll
            for (int t = 8; t < 16; t++) {
                half8_t af[4];
                #pragma unroll
                for (int rb = 0; rb < 4; rb++)
                    af[rb] = *(const half8_t*)(&xT[((t * 4 + rb) * 64 + lane) * 8]);
                #pragma unroll
                for (int cb = 0; cb < 2; cb++) {
                    const half8_t bf = *(const half8_t*)(wp + t * 512 + cb * 8192);
                    #pragma unroll
                    for (int rb = 0; rb < 4; rb++)
                        acc1[rb][cb] = __builtin_amdgcn_mfma_f32_16x16x32_f16(af[rb], bf, acc1[rb][cb], 0, 0, 0);
                }
            }
        }
        if (hasS) { gemm0c(2); stage_write(3); }
        __syncthreads();

        // ---------------- s4: ep1 -> x2 frags ; gemm0 c3 ----------------
        if (hasS) stage_load(4);
        if (hasT) {
            #pragma unroll
            for (int cb = 0; cb < 2; cb++) {
                const int c = cl + 16 * (2 * wv + cb);
                const float sv = s1f[c], cv = c1f[c];
                const int t = c >> 5, j = c & 7, sc = 16 * ((c >> 3) & 3);
                #pragma unroll
                for (int rb = 0; rb < 4; rb++)
                    #pragma unroll
                    for (int v = 0; v < 4; v++) {
                        const int r = 16 * rb + 4 * grp + v;
                        float y = row_rs[r] * (acc1[rb][cb][v] - row_m[r] * sv) + cv;
                        y = y > 0.f ? y : (__expf(y) - 1.f);
                        xT[((t * 4 + rb) * 64 + (4 * grp + v + sc)) * 8 + j] = (half_t)y;
                    }
            }
        }
        if (hasS) { gemm0c(3); stage_write(4); }
        __syncthreads();

        // ---------------- s5: LN2 partials ; gemm0 c4 ----------------
        if (hasS) stage_load(5);
        if (hasT) {
            float s_ = 0.f, q_ = 0.f;
            #pragma unroll
            for (int u = 0; u < 4; u++) {
                const int t = 4 * th_s + u;
                const half8_t h = *(const half8_t*)(&xT[((t * 4 + rb_s) * 64 + lane) * 8]);
                half2_t p0 = {h[0], h[1]}, p1 = {h[2], h[3]}, p2 = {h[4], h[5]}, p3 = {h[6], h[7]};
                s_ = FDOT2(p0, one2, s_); s_ = FDOT2(p1, one2, s_);
                s_ = FDOT2(p2, one2, s_); s_ = FDOT2(p3, one2, s_);
                q_ = FDOT2(p0, p0, q_);   q_ = FDOT2(p1, p1, q_);
                q_ = FDOT2(p2, p2, q_);   q_ = FDOT2(p3, p3, q_);
            }
            s_ += __shfl_xor(s_, 16); s_ += __shfl_xor(s_, 32);
            q_ += __shfl_xor(q_, 16); q_ += __shfl_xor(q_, 32);
            if (lane < 16) { ps[th_s][16 * rb_s + lane] = s_; pq[th_s][16 * rb_s + lane] = q_; }
        }
        if (hasS) { gemm0c(4); stage_write(5); }
        __syncthreads();

        // ---------------- s6: LN2 combine + gemm2 ; gemm0 c5 ----------------
        if (hasS) stage_load(6);
        if (hasT) {
            if (tid < 64) {
                const float a_ = ps[0][tid] + ps[1][tid];
                const float b_ = pq[0][tid] + pq[1][tid];
                const float mm = a_ * (1.f / 256.f);
                row_m[tid]  = mm;
                row_rs[tid] = 1.f / sqrtf(b_ * (1.f / 256.f) - mm * mm + LN_EPS);
            }
            #pragma unroll
            for (int rb = 0; rb < 4; rb++) acc2[rb] = 0.f;
            const half_t* wp = W2p + (size_t)(wv * 8) * 512 + lane * 8;
            #pragma unroll
            for (int t = 0; t < 8; t++) {
                half8_t af[4];
                #pragma unroll
                for (int rb = 0; rb < 4; rb++)
                    af[rb] = *(const half8_t*)(&xT[((t * 4 + rb) * 64 + lane) * 8]);
                const half8_t bf = *(const half8_t*)(wp + t * 512);
                #pragma unroll
                for (int rb = 0; rb < 4; rb++)
                    acc2[rb] = __builtin_amdgcn_mfma_f32_16x16x32_f16(af[rb], bf, acc2[rb], 0, 0, 0);
            }
        }
        if (hasS) { gemm0c(5); stage_write(6); }
        __syncthreads();

        // ---------------- s7: ep2 -> y3 tile ; gemm0 c6 ----------------
        if (hasS) stage_load(7);
        if (hasT) {
            const int c2i = cl + 16 * wv;
            const float sv = s2f[c2i], cv = c2f[c2i];
            half_t* y3 = xT + 16384;
            #pragma unroll
            for (int rb = 0; rb < 4; rb++)
                #pragma unroll
                for (int v = 0; v < 4; v++) {
                    const int r = 16 * rb + 4 * grp + v;
                    float y = row_rs[r] * (acc2[rb][v] - row_m[r] * sv) + cv;
                    y = y > 0.f ? y : (__expf(y) - 1.f);
                    y3[r * 136 + c2i] = (half_t)y;
                }
        }
        if (hasS) { gemm0c(6); stage_write(7); }
        __syncthreads();

        // ---------------- s8: LN3 + out(t_{i-1}) ; gemm0 c7 ; LN0 finalize ----------------
        if (hasT) {
            const half_t* y3 = xT + 16384;
            float s_ = 0.f, q_ = 0.f, d_ = 0.f;
            #pragma unroll
            for (int u = 0; u < 2; u++) {
                const int cb = jj * 16 + 8 * u;
                const int wi = cb >> 1;
                const half8_t h = *(const half8_t*)(y3 + row * 136 + cb);
                half2_t p0 = {h[0], h[1]}, p1 = {h[2], h[3]}, p2 = {h[4], h[5]}, p3 = {h[6], h[7]};
                s_ = FDOT2(p0, one2, s_); s_ = FDOT2(p1, one2, s_);
                s_ = FDOT2(p2, one2, s_); s_ = FDOT2(p3, one2, s_);
                q_ = FDOT2(p0, p0, q_);   q_ = FDOT2(p1, p1, q_);
                q_ = FDOT2(p2, p2, q_);   q_ = FDOT2(p3, p3, q_);
                d_ = FDOT2(p0, w3h[wi], d_);     d_ = FDOT2(p1, w3h[wi + 1], d_);
                d_ = FDOT2(p2, w3h[wi + 2], d_); d_ = FDOT2(p3, w3h[wi + 3], d_);
            }
            s_ += __shfl_xor(s_, 1); s_ += __shfl_xor(s_, 2); s_ += __shfl_xor(s_, 4);
            q_ += __shfl_xor(q_, 1); q_ += __shfl_xor(q_, 2); q_ += __shfl_xor(q_, 4);
            d_ += __shfl_xor(d_, 1); d_ += __shfl_xor(d_, 2); d_ += __shfl_xor(d_, 4);
            if (jj == 0) {
                const float mm = s_ * (1.f / 128.f);
                const float rs = 1.f / sqrtf(q_ * (1.f / 128.f) - mm * mm + LN_EPS);
                out[(tile0 + i - 1) * 64 + row] = rs * (d_ - mm * f[1920]) + f[1921];
            }
        }
        if (hasS) {
            gemm0c(7);
            // LN0 finalize for tile i (stats complete after chunk 7 staged)
            s  += __shfl_xor(s, 1);  s  += __shfl_xor(s, 2);  s  += __shfl_xor(s, 4);
            ss += __shfl_xor(ss, 1); ss += __shfl_xor(ss, 2); ss += __shfl_xor(ss, 4);
            if (jj == 0) {
                const float mm = s * (1.f / 768.f);
                row_m0[row]  = mm;
                row_rs0[row] = 1.f / sqrtf(ss * (1.f / 768.f) - mm * mm + LN_EPS);
            }
            s = 0.f; ss = 0.f;
        }
        __syncthreads();
    }
}

extern "C" void kernel_launch(void* const* d_in, const int* in_sizes, int n_in,
                              void* d_out, int out_size, void* d_ws, size_t ws_size,
                              hipStream_t stream) {
    const float* x  = (const float*)d_in[0];
    const float* g0 = (const float*)d_in[1];
    const float* b0 = (const float*)d_in[2];
    const float* W0 = (const float*)d_in[3];
    const float* c0 = (const float*)d_in[4];
    const float* g1 = (const float*)d_in[5];
    const float* b1 = (const float*)d_in[6];
    const float* W1 = (const float*)d_in[7];
    const float* c1 = (const float*)d_in[8];
    const float* g2 = (const float*)d_in[9];
    const float* b2 = (const float*)d_in[10];
    const float* W2 = (const float*)d_in[11];
    const float* c2 = (const float*)d_in[12];
    const float* g3 = (const float*)d_in[13];
    const float* b3 = (const float*)d_in[14];
    const float* W3 = (const float*)d_in[15];
    const float* c3 = (const float*)d_in[16];

    half_t* ws = (half_t*)d_ws;            // packed weights: 557056 halves
    float*  f  = (float*)(ws + 557056);    // folded scalars: 1922 floats

    pack_weights<<<272, 256, 0, stream>>>(W0, g0, W1, g1, W2, g2, ws);
    fold_bias<<<225, 256, 0, stream>>>(W0, g0, b0, c0, W1, g1, b1, c1,
                                       W2, g2, b2, c2, W3, g3, b3, c3, f);

    const int nrows  = in_sizes[0] / 768;  // 262144
    const int ntiles = (nrows / 64) / 256; // 16 tiles per block
    fused_mlp<<<256, 512, 0, stream>>>(
        x, ws, ws + 393216, ws + 524288, f, (float*)d_out, ntiles);
}

// Round 11
// 482.227 us; speedup vs baseline: 2.0959x; 2.0959x over previous
//
#include <hip/hip_runtime.h>
#include <hip/hip_fp16.h>
#include <math.h>

typedef _Float16 half_t;
typedef half_t half2_t __attribute__((ext_vector_type(2)));
typedef half_t half4_t __attribute__((ext_vector_type(4)));
typedef half_t half8_t __attribute__((ext_vector_type(8)));
typedef float f32x4 __attribute__((ext_vector_type(4)));

#define LN_EPS 1e-5f
#define FDOT2(a, b, c) __builtin_amdgcn_fdot2((a), (b), (c), false)

// ---------------------------------------------------------------------------
// Pack W*g (LN gain folded) into f16 MFMA B-fragment order.
// ---------------------------------------------------------------------------
__global__ void pack_weights(const float* __restrict__ W0, const float* __restrict__ g0,
                             const float* __restrict__ W1, const float* __restrict__ g1,
                             const float* __restrict__ W2, const float* __restrict__ g2,
                             half_t* __restrict__ ws) {
    int sid = blockIdx.x * 256 + threadIdx.x;
    const float* W; const float* g; int K, T, off;
    if (sid < 49152)      { W = W0; g = g0; K = 768; T = 24; off = 0; }
    else if (sid < 65536) { W = W1; g = g1; K = 512; T = 16; off = 49152; sid -= 49152; }
    else if (sid < 69632) { W = W2; g = g2; K = 256; T = 8;  off = 65536; sid -= 65536; }
    else return;
    const int l   = sid & 63;
    const int t   = (sid >> 6) % T;
    const int cbg = (sid >> 6) / T;
    const int n   = (l & 15) + 16 * cbg;
    const int k0  = 32 * t + 8 * (l >> 4);
    const float* src = W + (size_t)n * K + k0;
    const float* gs  = g + k0;
    half8_t v;
    #pragma unroll
    for (int jq = 0; jq < 8; jq++) v[jq] = (half_t)(src[jq] * gs[jq]);
    *(half8_t*)(ws + (size_t)(off + sid) * 8) = v;
}

// ---------------------------------------------------------------------------
// Fold LN bias into per-output scalars. f layout:
// s0[512] c0[512] s1[256] c1[256] s2[128] c2[128] w3g[128] s3 c3'
// ---------------------------------------------------------------------------
__global__ void fold_bias(const float* __restrict__ W0, const float* __restrict__ g0,
                          const float* __restrict__ b0, const float* __restrict__ c0,
                          const float* __restrict__ W1, const float* __restrict__ g1,
                          const float* __restrict__ b1, const float* __restrict__ c1,
                          const float* __restrict__ W2, const float* __restrict__ g2,
                          const float* __restrict__ b2, const float* __restrict__ c2,
                          const float* __restrict__ W3, const float* __restrict__ g3,
                          const float* __restrict__ b3, const float* __restrict__ c3,
                          float* __restrict__ f) {
    const int gw   = (blockIdx.x * 256 + threadIdx.x) >> 6;
    const int lane = threadIdx.x & 63;
    if (gw == 896) {
        float s = 0.f, cb_ = 0.f;
        for (int k = lane; k < 128; k += 64) {
            const float wg = W3[k] * g3[k];
            f[1792 + k] = wg;
            s += wg; cb_ += W3[k] * b3[k];
        }
        #pragma unroll
        for (int m = 1; m < 64; m <<= 1) { s += __shfl_xor(s, m); cb_ += __shfl_xor(cb_, m); }
        if (lane == 0) { f[1920] = s; f[1921] = cb_ + c3[0]; }
        return;
    }
    const float *W, *g, *b, *cc; int K, n; float *sf, *cf;
    if (gw < 512)      { W = W0; g = g0; b = b0; cc = c0; K = 768; n = gw;       sf = f;        cf = f + 512; }
    else if (gw < 768) { W = W1; g = g1; b = b1; cc = c1; K = 512; n = gw - 512; sf = f + 1024; cf = f + 1280; }
    else if (gw < 896) { W = W2; g = g2; b = b2; cc = c2; K = 256; n = gw - 768; sf = f + 1536; cf = f + 1664; }
    else return;
    const float* Wr = W + (size_t)n * K;
    float s = 0.f, cb_ = 0.f;
    for (int k = lane; k < K; k += 64) { const float wg = Wr[k] * g[k]; s += wg; cb_ += Wr[k] * b[k]; }
    #pragma unroll
    for (int m = 1; m < 64; m <<= 1) { s += __shfl_xor(s, m); cb_ += __shfl_xor(cb_, m); }
    if (lane == 0) { sf[n] = s; cf[n] = cb_ + cc[n]; }
}

// ---------------------------------------------------------------------------
// Fused MLP v11: two-tile in-block interleave. Block = 128 rows (tiles A,B),
// 512 threads, 1 block/CU (LDS 104 KB). Phase1: head(A). Phase2: each slice =
// {stage_load(B) ; tail-piece(A) ; gemm0(B) ; stage_write(B)}. Phase3: tail(B).
// Tail uses xreg (64 KB x1 -> x2 -> y3); head uses stg2 (32 KB dbuf).
// ---------------------------------------------------------------------------
__global__ __launch_bounds__(512, 2)
void fused_mlp(const float* __restrict__ x_in,
               const half_t* __restrict__ W0p, const half_t* __restrict__ W1p,
               const half_t* __restrict__ W2p, const float* __restrict__ f,
               float* __restrict__ out)
{
    __shared__ half_t xreg[32768];     // 64 KiB tail region: x1 / x2 / y3
    __shared__ half_t stg2[16384];     // 32 KiB head staging dbuf (2 x 128-col chunks)
    __shared__ float rmA[64], rsA[64], rmB[64], rsB[64];
    __shared__ float ps[8][64], pq[8][64];
    __shared__ half2_t w3h[64];

    const int tid  = threadIdx.x;
    const int lane = tid & 63;
    const int wv   = tid >> 6;
    const int grp  = lane >> 4;
    const int cl   = lane & 15;
    const int row  = tid >> 3;
    const int jj   = tid & 7;
    const int rbw  = row >> 4;
    const long r0  = (long)blockIdx.x * 128;
    const float* xrA = x_in + (r0 + row) * 768;
    const float* xrB = xrA + 64 * 768;

    const float* s0f = f;        const float* c0f = f + 512;
    const float* s1f = f + 1024; const float* c1f = f + 1280;
    const float* s2f = f + 1536; const float* c2f = f + 1664;
    const half2_t one2 = {(half_t)1.f, (half_t)1.f};

    if (tid < 64) {
        half2_t w; w[0] = (half_t)f[1792 + 2 * tid]; w[1] = (half_t)f[1793 + 2 * tid];
        w3h[tid] = w;
    }

    float sA = 0.f, ssA = 0.f, sB = 0.f, ssB = 0.f;
    f32x4 vb[4];
    f32x4 acc0[4][4];     // time-shared: A's gemm0 (phase1..S1), then B's (S2..P1)
    f32x4 acc1[4][2];
    f32x4 acc2[4];

    auto zacc0 = [&]() {
        #pragma unroll
        for (int rb = 0; rb < 4; rb++)
            #pragma unroll
            for (int cb = 0; cb < 4; cb++) acc0[rb][cb] = 0.f;
    };

    auto stage_load = [&](const float* xr, int c) {
        const float* xp = xr + 128 * c + 4 * jj;
        #pragma unroll
        for (int i = 0; i < 4; i++)
            vb[i] = __builtin_nontemporal_load((const f32x4*)(xp + 32 * i));
    };
    auto stage_write = [&](int c, float& s_, float& ss_) {
        half_t* fb = stg2 + 8192 * (c & 1);
        const int hg = jj >> 1, jo = 4 * (jj & 1);
        #pragma unroll
        for (int i = 0; i < 4; i++) {
            const f32x4 v = vb[i];
            half2_t h01; h01[0] = (half_t)v[0]; h01[1] = (half_t)v[1];
            half2_t h23; h23[0] = (half_t)v[2]; h23[1] = (half_t)v[3];
            s_  = FDOT2(h01, one2, s_);  s_  = FDOT2(h23, one2, s_);
            ss_ = FDOT2(h01, h01, ss_);  ss_ = FDOT2(h23, h23, ss_);
            half4_t hv; hv[0] = h01[0]; hv[1] = h01[1]; hv[2] = h23[0]; hv[3] = h23[1];
            *(half4_t*)(&fb[((i * 4 + rbw) * 64 + ((row & 15) + 16 * hg)) * 8 + jo]) = hv;
        }
    };
    auto ln0_fin = [&](float& s_, float& ss_, float* rm, float* rs) {
        s_  += __shfl_xor(s_, 1);  s_  += __shfl_xor(s_, 2);  s_  += __shfl_xor(s_, 4);
        ss_ += __shfl_xor(ss_, 1); ss_ += __shfl_xor(ss_, 2); ss_ += __shfl_xor(ss_, 4);
        if (jj == 0) {
            const float mm = s_ * (1.f / 768.f);
            rm[row] = mm;
            rs[row] = 1.f / sqrtf(ss_ * (1.f / 768.f) - mm * mm + LN_EPS);
        }
    };
    auto gemm0c = [&](int c) {
        const half_t* fb = stg2 + 8192 * (c & 1);
        const half_t* wp = W0p + (size_t)(4 * wv * 24 + 4 * c) * 512 + lane * 8;
        half8_t bA[4], bB[4];
        #pragma unroll
        for (int cb = 0; cb < 4; cb++) bA[cb] = *(const half8_t*)(wp + cb * 12288);
        #pragma unroll
        for (int tt = 0; tt < 4; tt++) {
            half8_t* cur = (tt & 1) ? bB : bA;
            half8_t* nxt = (tt & 1) ? bA : bB;
            if (tt < 3) {
                #pragma unroll
                for (int cb = 0; cb < 4; cb++)
                    nxt[cb] = *(const half8_t*)(wp + (tt + 1) * 512 + cb * 12288);
            }
            half8_t af[4];
            #pragma unroll
            for (int rb = 0; rb < 4; rb++)
                af[rb] = *(const half8_t*)(&fb[((tt * 4 + rb) * 64 + lane) * 8]);
            #pragma unroll
            for (int cb = 0; cb < 4; cb++)
                #pragma unroll
                for (int rb = 0; rb < 4; rb++)
                    acc0[rb][cb] = __builtin_amdgcn_mfma_f32_16x16x32_f16(af[rb], cur[cb], acc0[rb][cb], 0, 0, 0);
        }
    };
    // tail piece 1: LN0 fold + ELU + LN1 partials (shuffle) + full x1 write
    auto ep0 = [&](const float* rm0, const float* rs0) {
        float sv[4], cv[4];
        #pragma unroll
        for (int cb = 0; cb < 4; cb++) {
            const int c = cl + 16 * (4 * wv + cb);
            sv[cb] = s0f[c]; cv[cb] = c0f[c];
        }
        #pragma unroll
        for (int rb = 0; rb < 4; rb++)
            #pragma unroll
            for (int v = 0; v < 4; v++) {
                const int r = 16 * rb + 4 * grp + v;
                const float rm = rm0[r], rr = rs0[r];
                float a_ = 0.f, q_ = 0.f;
                #pragma unroll
                for (int cb = 0; cb < 4; cb++) {
                    float y = rr * (acc0[rb][cb][v] - rm * sv[cb]) + cv[cb];
                    y = y > 0.f ? y : (__expf(y) - 1.f);
                    acc0[rb][cb][v] = y;
                    a_ += y; q_ += y * y;
                }
                a_ += __shfl_xor(a_, 1); a_ += __shfl_xor(a_, 2); a_ += __shfl_xor(a_, 4); a_ += __shfl_xor(a_, 8);
                q_ += __shfl_xor(q_, 1); q_ += __shfl_xor(q_, 2); q_ += __shfl_xor(q_, 4); q_ += __shfl_xor(q_, 8);
                if (cl == 0) { ps[wv][r] = a_; pq[wv][r] = q_; }
            }
        #pragma unroll
        for (int cb = 0; cb < 4; cb++) {
            const int c = cl + 16 * (4 * wv + cb);
            const int t = c >> 5, j = c & 7, sc = 16 * ((c >> 3) & 3);
            #pragma unroll
            for (int rb = 0; rb < 4; rb++)
                #pragma unroll
                for (int v = 0; v < 4; v++)
                    xreg[((t * 4 + rb) * 64 + (4 * grp + v + sc)) * 8 + j] = (half_t)acc0[rb][cb][v];
        }
    };
    auto combine = [&](float* rm, float* rs, float inv) {
        if (tid < 64) {
            float a_ = 0.f, q_ = 0.f;
            #pragma unroll
            for (int w = 0; w < 8; w++) { a_ += ps[w][tid]; q_ += pq[w][tid]; }
            const float mm = a_ * inv;
            rm[tid] = mm;
            rs[tid] = 1.f / sqrtf(q_ * inv - mm * mm + LN_EPS);
        }
    };
    auto gemm1 = [&]() {
        #pragma unroll
        for (int rb = 0; rb < 4; rb++) { acc1[rb][0] = 0.f; acc1[rb][1] = 0.f; }
        const half_t* wp = W1p + (size_t)(2 * wv * 16) * 512 + lane * 8;
        half8_t bA[2], bB[2];
        bA[0] = *(const half8_t*)(wp);
        bA[1] = *(const half8_t*)(wp + 8192);
        #pragma unroll
        for (int t = 0; t < 16; t++) {
            half8_t* cur = (t & 1) ? bB : bA;
            half8_t* nxt = (t & 1) ? bA : bB;
            if (t < 15) {
                nxt[0] = *(const half8_t*)(wp + (t + 1) * 512);
                nxt[1] = *(const half8_t*)(wp + (t + 1) * 512 + 8192);
            }
            half8_t af[4];
            #pragma unroll
            for (int rb = 0; rb < 4; rb++)
                af[rb] = *(const half8_t*)(&xreg[((t * 4 + rb) * 64 + lane) * 8]);
            #pragma unroll
            for (int cb = 0; cb < 2; cb++)
                #pragma unroll
                for (int rb = 0; rb < 4; rb++)
                    acc1[rb][cb] = __builtin_amdgcn_mfma_f32_16x16x32_f16(af[rb], cur[cb], acc1[rb][cb], 0, 0, 0);
        }
    };
    // tail piece 3: LN1 fold + ELU + LN2 partials + x2 write
    auto ep1 = [&](const float* rm1, const float* rs1) {
        float sv[2], cv[2];
        #pragma unroll
        for (int cb = 0; cb < 2; cb++) {
            const int c = cl + 16 * (2 * wv + cb);
            sv[cb] = s1f[c]; cv[cb] = c1f[c];
        }
        #pragma unroll
        for (int rb = 0; rb < 4; rb++)
            #pragma unroll
            for (int v = 0; v < 4; v++) {
                const int r = 16 * rb + 4 * grp + v;
                const float rm = rm1[r], rr = rs1[r];
                float a_ = 0.f, q_ = 0.f;
                #pragma unroll
                for (int cb = 0; cb < 2; cb++) {
                    float y = rr * (acc1[rb][cb][v] - rm * sv[cb]) + cv[cb];
                    y = y > 0.f ? y : (__expf(y) - 1.f);
                    acc1[rb][cb][v] = y;
                    a_ += y; q_ += y * y;
                }
                a_ += __shfl_xor(a_, 1); a_ += __shfl_xor(a_, 2); a_ += __shfl_xor(a_, 4); a_ += __shfl_xor(a_, 8);
                q_ += __shfl_xor(q_, 1); q_ += __shfl_xor(q_, 2); q_ += __shfl_xor(q_, 4); q_ += __shfl_xor(q_, 8);
                if (cl == 0) { ps[wv][r] = a_; pq[wv][r] = q_; }
            }
        #pragma unroll
        for (int cb = 0; cb < 2; cb++) {
            const int c = cl + 16 * (2 * wv + cb);
            const int t = c >> 5, j = c & 7, sc = 16 * ((c >> 3) & 3);
            #pragma unroll
            for (int rb = 0; rb < 4; rb++)
                #pragma unroll
                for (int v = 0; v < 4; v++)
                    xreg[((t * 4 + rb) * 64 + (4 * grp + v + sc)) * 8 + j] = (half_t)acc1[rb][cb][v];
        }
    };
    auto gemm2 = [&]() {
        #pragma unroll
        for (int rb = 0; rb < 4; rb++) acc2[rb] = 0.f;
        const half_t* wp = W2p + (size_t)(wv * 8) * 512 + lane * 8;
        half8_t bA = *(const half8_t*)(wp);
        #pragma unroll
        for (int t = 0; t < 8; t++) {
            const half8_t cur = bA;
            if (t < 7) bA = *(const half8_t*)(wp + (t + 1) * 512);
            half8_t af[4];
            #pragma unroll
            for (int rb = 0; rb < 4; rb++)
                af[rb] = *(const half8_t*)(&xreg[((t * 4 + rb) * 64 + lane) * 8]);
            #pragma unroll
            for (int rb = 0; rb < 4; rb++)
                acc2[rb] = __builtin_amdgcn_mfma_f32_16x16x32_f16(af[rb], cur, acc2[rb], 0, 0, 0);
        }
    };
    // tail piece 5: LN2 fold + ELU -> y3 tile [64][136]
    auto ep2 = [&](const float* rm2, const float* rs2) {
        const int c2i = cl + 16 * wv;
        const float sv = s2f[c2i], cv = c2f[c2i];
        #pragma unroll
        for (int rb = 0; rb < 4; rb++)
            #pragma unroll
            for (int v = 0; v < 4; v++) {
                const int r = 16 * rb + 4 * grp + v;
                const float rm = rm2[r], rr = rs2[r];
                float y = rr * (acc2[rb][v] - rm * sv) + cv;
                y = y > 0.f ? y : (__expf(y) - 1.f);
                xreg[r * 136 + c2i] = (half_t)y;
            }
    };
    auto lastout = [&](long rbase) {
        float s_ = 0.f, q_ = 0.f, d_ = 0.f;
        #pragma unroll
        for (int u = 0; u < 2; u++) {
            const int cb = jj * 16 + 8 * u;
            const int wi = cb >> 1;
            const half8_t h = *(const half8_t*)(xreg + row * 136 + cb);
            half2_t p0 = {h[0], h[1]}, p1 = {h[2], h[3]}, p2 = {h[4], h[5]}, p3 = {h[6], h[7]};
            s_ = FDOT2(p0, one2, s_); s_ = FDOT2(p1, one2, s_);
            s_ = FDOT2(p2, one2, s_); s_ = FDOT2(p3, one2, s_);
            q_ = FDOT2(p0, p0, q_);   q_ = FDOT2(p1, p1, q_);
            q_ = FDOT2(p2, p2, q_);   q_ = FDOT2(p3, p3, q_);
            d_ = FDOT2(p0, w3h[wi], d_);     d_ = FDOT2(p1, w3h[wi + 1], d_);
            d_ = FDOT2(p2, w3h[wi + 2], d_); d_ = FDOT2(p3, w3h[wi + 3], d_);
        }
        s_ += __shfl_xor(s_, 1); s_ += __shfl_xor(s_, 2); s_ += __shfl_xor(s_, 4);
        q_ += __shfl_xor(q_, 1); q_ += __shfl_xor(q_, 2); q_ += __shfl_xor(q_, 4);
        d_ += __shfl_xor(d_, 1); d_ += __shfl_xor(d_, 2); d_ += __shfl_xor(d_, 4);
        if (jj == 0) {
            const float mm = s_ * (1.f / 128.f);
            const float rs = 1.f / sqrtf(q_ * (1.f / 128.f) - mm * mm + LN_EPS);
            out[rbase + row] = rs * (d_ - mm * f[1920]) + f[1921];
        }
    };

    // ================= phase 1: head(A) =================
    zacc0();
    stage_load(xrA, 0); stage_write(0, sA, ssA);
    __syncthreads();
    #pragma unroll 1
    for (int c = 0; c < 6; c++) {
        if (c < 5) stage_load(xrA, c + 1);
        gemm0c(c);
        if (c < 5) stage_write(c + 1, sA, ssA);
        if (c == 4) ln0_fin(sA, ssA, rmA, rsA);
        __syncthreads();
    }

    // ================= phase 2: tail(A) || head(B) =================
    // S1
    stage_load(xrB, 0);
    ep0(rmA, rsA);
    stage_write(0, sB, ssB);
    __syncthreads();
    // S2
    stage_load(xrB, 1);
    combine(rmA, rsA, 1.f / 512.f);
    zacc0();
    gemm1();
    gemm0c(0);
    stage_write(1, sB, ssB);
    __syncthreads();
    // S3
    stage_load(xrB, 2);
    ep1(rmA, rsA);
    gemm0c(1);
    stage_write(2, sB, ssB);
    __syncthreads();
    // S4
    stage_load(xrB, 3);
    combine(rmA, rsA, 1.f / 256.f);
    gemm2();
    gemm0c(2);
    stage_write(3, sB, ssB);
    __syncthreads();
    // S5
    stage_load(xrB, 4);
    ep2(rmA, rsA);
    gemm0c(3);
    stage_write(4, sB, ssB);
    __syncthreads();
    // S6
    stage_load(xrB, 5);
    lastout(r0);
    gemm0c(4);
    stage_write(5, sB, ssB);
    ln0_fin(sB, ssB, rmB, rsB);
    __syncthreads();
    // S7
    gemm0c(5);
    __syncthreads();

    // ================= phase 3: tail(B) =================
    ep0(rmB, rsB);
    __syncthreads();
    combine(rmB, rsB, 1.f / 512.f);
    gemm1();
    __syncthreads();
    ep1(rmB, rsB);
    __syncthreads();
    combine(rmB, rsB, 1.f / 256.f);
    gemm2();
    __syncthreads();
    ep2(rmB, rsB);
    __syncthreads();
    lastout(r0 + 64);
}

extern "C" void kernel_launch(void* const* d_in, const int* in_sizes, int n_in,
                              void* d_out, int out_size, void* d_ws, size_t ws_size,
                              hipStream_t stream) {
    const float* x  = (const float*)d_in[0];
    const float* g0 = (const float*)d_in[1];
    const float* b0 = (const float*)d_in[2];
    const float* W0 = (const float*)d_in[3];
    const float* c0 = (const float*)d_in[4];
    const float* g1 = (const float*)d_in[5];
    const float* b1 = (const float*)d_in[6];
    const float* W1 = (const float*)d_in[7];
    const float* c1 = (const float*)d_in[8];
    const float* g2 = (const float*)d_in[9];
    const float* b2 = (const float*)d_in[10];
    const float* W2 = (const float*)d_in[11];
    const float* c2 = (const float*)d_in[12];
    const float* g3 = (const float*)d_in[13];
    const float* b3 = (const float*)d_in[14];
    const float* W3 = (const float*)d_in[15];
    const float* c3 = (const float*)d_in[16];

    half_t* ws = (half_t*)d_ws;            // packed weights: 557056 halves
    float*  f  = (float*)(ws + 557056);    // folded scalars: 1922 floats

    pack_weights<<<272, 256, 0, stream>>>(W0, g0, W1, g1, W2, g2, ws);
    fold_bias<<<225, 256, 0, stream>>>(W0, g0, b0, c0, W1, g1, b1, c1,
                                       W2, g2, b2, c2, W3, g3, b3, c3, f);

    const int nrows = in_sizes[0] / 768;   // 262144
    fused_mlp<<<nrows / 128, 512, 0, stream>>>(
        x, ws, ws + 393216, ws + 524288, f, (float*)d_out);
}